// Round 17
// baseline (288.589 us; speedup 1.0000x reference)
//
#include <hip/hip_runtime.h>
#include <hip/hip_bf16.h>

#define B_   64
#define N_   512
#define T_   8
#define DIN_ 2
#define H_   256
#define L_   3
#define E_   8192
#define M_   128
#define P2_  24   // P*2
#define EPS_ 1e-5f

#define WTPAD 136

typedef __attribute__((ext_vector_type(8))) short short8;
typedef __attribute__((ext_vector_type(4))) float floatx4;

__device__ __forceinline__ unsigned short f2bf(float f) {
    union { float f; unsigned u; } v; v.f = f;
    unsigned r = v.u + 0x7FFF + ((v.u >> 16) & 1);
    return (unsigned short)(r >> 16);
}
__device__ __forceinline__ float bf2f(unsigned short h) {
    union { unsigned u; float f; } v; v.u = (unsigned)h << 16; return v.f;
}

// ===== prep: encoder (256 blks) + incidence build (512 blks) + thetaT (48) ==
__global__ __launch_bounds__(512, 4) void prep_kernel(
    const float* __restrict__ obs, const float* __restrict__ Wenc,
    const float* __restrict__ benc,
    unsigned short* __restrict__ actT, long actLo,
    const int* __restrict__ idx, unsigned short* __restrict__ Hmat,
    unsigned short* __restrict__ HmatT, float* __restrict__ DinvN,
    float* __restrict__ degP,
    const float* __restrict__ thetas, unsigned short* __restrict__ thT, long thLo)
{
    __shared__ __align__(16) char u[33024];
    int bid = blockIdx.x, tid = threadIdx.x;
    if (bid < 256) {
        float* ot = (float*)u;   // [16][513]
        int x8 = bid & 7, s = bid >> 3;
        int b = ((s >> 2) << 3) | x8;      // all 4 h-chunks of b on XCD b%8
        int h0 = (s & 3) * 64;
        const float4* src = (const float4*)(obs + (long)b * N_ * 16);
        for (int i = tid; i < 2048; i += 512) {
            float4 v = src[i];
            int n = i >> 2, k4 = (i & 3) << 2;
            ot[(k4 + 0) * 513 + n] = v.x;
            ot[(k4 + 1) * 513 + n] = v.y;
            ot[(k4 + 2) * 513 + n] = v.z;
            ot[(k4 + 3) * 513 + n] = v.w;
        }
        __syncthreads();
        int wave = tid >> 6, lane = tid & 63;
        int cbase = h0 + wave * 8;
        float w0[8], w1[8], bb[8];
#pragma unroll
        for (int i = 0; i < 8; ++i) {
            w0[i] = Wenc[cbase + i];
            w1[i] = Wenc[H_ + cbase + i];
            bb[i] = benc[cbase + i];
        }
        for (int j = 0; j < 8; ++j) {
            int n = j * 64 + lane;
            float x0[8], x1[8];
#pragma unroll
            for (int t = 0; t < 8; ++t) {
                x0[t] = ot[(2 * t) * 513 + n];
                x1[t] = ot[(2 * t + 1) * 513 + n];
            }
#pragma unroll
            for (int i = 0; i < 8; ++i) {
                float acc = 0.f;
#pragma unroll
                for (int t = 0; t < 8; ++t)
                    acc += fmaxf(x0[t] * w0[i] + x1[t] * w1[i] + bb[i], 0.f);
                acc *= 0.125f;
                long o = ((long)b * H_ + cbase + i) * N_ + n;
                unsigned short hv = f2bf(acc);
                actT[o] = hv;
                actT[actLo + o] = f2bf(acc - bf2f(hv));
            }
        }
    } else if (bid < 768) {
        unsigned* cnt = (unsigned*)u;    // [64][129]
        int id2 = bid - 256;
        int x8 = id2 & 7, s = id2 >> 3;
        int b = ((s >> 3) << 3) | x8;    // all 8 chunks of b on XCD b%8
        int chunk = s & 7;
        int c0 = chunk * 64;
        for (int i = tid; i < 64 * 129; i += 512) cnt[i] = 0;
        __syncthreads();
        const int* nodes = idx + (long)b * 2 * E_;
        const int* edges = nodes + E_;
        for (int e = tid; e < E_; e += 512) {
            int n = nodes[e];
            if ((n >> 6) == chunk) atomicAdd(&cnt[(n & 63) * 129 + edges[e]], 1u);
        }
        __syncthreads();
        for (int i = tid; i < 64 * 128; i += 512) {
            int r = i >> 7, m = i & 127;
            Hmat[((long)(b * N_ + c0 + r)) * M_ + m] = f2bf((float)cnt[r * 129 + m]);
        }
        for (int i = tid; i < 64 * 128; i += 512) {
            int m = i >> 6, r = i & 63;
            HmatT[((long)(b * M_ + m)) * N_ + c0 + r] = f2bf((float)cnt[r * 129 + m]);
        }
        if (tid < 64) {
            unsigned s2 = 0;
#pragma unroll 8
            for (int m = 0; m < 128; ++m) s2 += cnt[tid * 129 + m];
            DinvN[b * N_ + c0 + tid] = 1.0f / fmaxf((float)s2, 1.0f);
        } else if (tid < 192) {
            int m = tid - 64;
            unsigned s2 = 0;
#pragma unroll 8
            for (int r = 0; r < 64; ++r) s2 += cnt[r * 129 + m];
            degP[((long)b * 8 + chunk) * M_ + m] = (float)s2;
        }
    } else {
        float (*tile)[65] = (float(*)[65])u;
        int sub = bid - 768;                 // 0..47
        int cx = sub & 3, ry = (sub >> 2) & 3, l = sub >> 4;
        int r0 = ry * 64, c0 = cx * 64;
        const float* ib = thetas + (long)l * H_ * H_;
        unsigned short* ob = thT + (long)l * H_ * H_;
        int x = tid & 63, y0 = tid >> 6;
#pragma unroll
        for (int i = 0; i < 8; ++i) {
            int y = y0 * 8 + i;
            tile[y][x] = ib[(long)(r0 + y) * H_ + c0 + x];
        }
        __syncthreads();
#pragma unroll
        for (int i = 0; i < 8; ++i) {
            int y = y0 * 8 + i;
            float v = tile[x][y];
            unsigned short hv = f2bf(v);
            long o = (long)(c0 + y) * H_ + r0 + x;
            ob[o] = hv;
            ob[thLo + o] = f2bf(v - bf2f(hv));
        }
    }
}

// ===== z: Z[m][h'] = Binv[m] * sum_n HT[m][n]*act[h'][n], split out =======
// Direct-from-global (XCD-L2-resident) MFMA operands: no LDS staging, 1 barrier.
__global__ __launch_bounds__(256, 4) void z_kernel(
    const unsigned short* __restrict__ HmatT,
    const unsigned short* __restrict__ actIn, long actLo,
    const float* __restrict__ degP,
    unsigned short* __restrict__ Zg, long zLo)
{
    __shared__ float binv[128];
    int b = blockIdx.x, hs = blockIdx.y * 64;
    int tid = threadIdx.x, wave = tid >> 6, lane = tid & 63;
    int lr = lane & 15, lq = lane >> 4;
    int wm = (wave & 1) * 64, wn = (wave >> 1) * 32;
    const unsigned short* HT   = HmatT + (long)b * M_ * N_;
    const unsigned short* aInH = actIn + (long)b * H_ * N_ + (long)hs * N_;
    const unsigned short* aInL = actIn + actLo + (long)b * H_ * N_ + (long)hs * N_;

    if (tid < 128) {
        float s = 0.f;
        const float* dp = degP + (long)b * 8 * M_ + tid;
#pragma unroll
        for (int c = 0; c < 8; ++c) s += dp[c * M_];
        binv[tid] = 1.0f / fmaxf(s, 1.0f);
    }
    __syncthreads();

    // fragment row bases (lane-fixed)
    const unsigned short* aRow[4];
#pragma unroll
    for (int mt = 0; mt < 4; ++mt)
        aRow[mt] = HT + (long)(wm + mt * 16 + lr) * N_ + lq * 8;
    const unsigned short* bRowH[2];
    const unsigned short* bRowL[2];
#pragma unroll
    for (int nt = 0; nt < 2; ++nt) {
        bRowH[nt] = aInH + (long)(wn + nt * 16 + lr) * N_ + lq * 8;
        bRowL[nt] = aInL + (long)(wn + nt * 16 + lr) * N_ + lq * 8;
    }

    floatx4 acc[4][2] = {};
    for (int k0 = 0; k0 < N_; k0 += 32) {
        short8 af[4], bh[2], bl[2];
#pragma unroll
        for (int mt = 0; mt < 4; ++mt)
            af[mt] = *(const short8*)(aRow[mt] + k0);
#pragma unroll
        for (int nt = 0; nt < 2; ++nt) {
            bh[nt] = *(const short8*)(bRowH[nt] + k0);
            bl[nt] = *(const short8*)(bRowL[nt] + k0);
        }
#pragma unroll
        for (int mt = 0; mt < 4; ++mt)
#pragma unroll
            for (int nt = 0; nt < 2; ++nt) {
                acc[mt][nt] = __builtin_amdgcn_mfma_f32_16x16x32_bf16(
                    af[mt], bh[nt], acc[mt][nt], 0, 0, 0);
                acc[mt][nt] = __builtin_amdgcn_mfma_f32_16x16x32_bf16(
                    af[mt], bl[nt], acc[mt][nt], 0, 0, 0);
            }
    }
#pragma unroll
    for (int mt = 0; mt < 4; ++mt)
#pragma unroll
        for (int r4 = 0; r4 < 4; ++r4) {
            int m = wm + mt * 16 + lq * 4 + r4;
            float rsB = binv[m];
#pragma unroll
            for (int nt = 0; nt < 2; ++nt) {
                float v = acc[mt][nt][r4] * rsB;
                unsigned short hv = f2bf(v);
                long o = ((long)b * M_ + m) * H_ + hs + wn + nt * 16 + lr;
                Zg[o] = hv;
                Zg[zLo + o] = f2bf(v - bf2f(hv));
            }
        }
}

// ===== wh: W=Theta^T Z^T ; hc^T=Dinv(W Hm^T)+cb ; BN ; ReLU ; split write ==
// Stage-2 operands (thT, Zg) read directly from global (L2); 3 barriers total.
__global__ __launch_bounds__(512, 4) void wh_kernel(
    const unsigned short* __restrict__ Zg, long zLo,
    const unsigned short* __restrict__ Hmat,
    const unsigned short* __restrict__ thT, long thLo,   // pre-offset to layer
    const float* __restrict__ DinvN, const float* __restrict__ convb,
    const float* __restrict__ gamma, const float* __restrict__ beta,
    unsigned short* __restrict__ actOut, long actLo)
{
    __shared__ __align__(16) unsigned short Wh[32 * WTPAD];
    __shared__ __align__(16) unsigned short Wl[32 * WTPAD];
    __shared__ float rsum[32 * 8];
    __shared__ float rsq[32 * 8];
    __shared__ float2 prm[32];

    int id = blockIdx.x;
    int xcd = id & 7, slot = id >> 3;
    int chunk = slot & 7;
    int b  = ((slot >> 3) << 3) | xcd;
    int h0 = chunk * 32;

    int tid = threadIdx.x, wave = tid >> 6, lane = tid & 63;
    int lr = lane & 15, lq = lane >> 4;
    const unsigned short* Zb = Zg + (long)b * M_ * H_;
    const unsigned short* Hm = Hmat + (long)b * N_ * M_;

    // ---- stage 2: W[h 32][m 128] = sum_h' thT[h][h'] * Z[m][h'] ----
    int wm2 = (wave >> 2) * 16, wn2 = (wave & 3) * 32;
    const unsigned short* thRowH = thT + (long)(h0 + wm2 + lr) * H_ + lq * 8;
    const unsigned short* thRowL = thRowH + thLo;
    const unsigned short* zRowH[2];
    const unsigned short* zRowL[2];
#pragma unroll
    for (int nt = 0; nt < 2; ++nt) {
        zRowH[nt] = Zb + (long)(wn2 + nt * 16 + lr) * H_ + lq * 8;
        zRowL[nt] = zRowH[nt] + zLo;
    }
    floatx4 acc2[2] = {};
    for (int k0 = 0; k0 < H_; k0 += 32) {
        short8 ah = *(const short8*)(thRowH + k0);
        short8 al = *(const short8*)(thRowL + k0);
        short8 zb[2], zl[2];
#pragma unroll
        for (int nt = 0; nt < 2; ++nt) {
            zb[nt] = *(const short8*)(zRowH[nt] + k0);
            zl[nt] = *(const short8*)(zRowL[nt] + k0);
        }
#pragma unroll
        for (int nt = 0; nt < 2; ++nt) {
            acc2[nt] = __builtin_amdgcn_mfma_f32_16x16x32_bf16(ah, zb[nt], acc2[nt], 0, 0, 0);
            acc2[nt] = __builtin_amdgcn_mfma_f32_16x16x32_bf16(ah, zl[nt], acc2[nt], 0, 0, 0);
            acc2[nt] = __builtin_amdgcn_mfma_f32_16x16x32_bf16(al, zb[nt], acc2[nt], 0, 0, 0);
        }
    }
#pragma unroll
    for (int r4 = 0; r4 < 4; ++r4) {
        int row = wm2 + lq * 4 + r4;
#pragma unroll
        for (int nt = 0; nt < 2; ++nt) {
            int col = wn2 + nt * 16 + lr;
            float v = acc2[nt][r4];
            unsigned short hv = f2bf(v);
            Wh[row * WTPAD + col] = hv;
            Wl[row * WTPAD + col] = f2bf(v - bf2f(hv));
        }
    }
    __syncthreads();

    // ---- stage 3: hc^T[h 32][n 512] = Dinv[n]*sum_m W[h][m]*Hm[n][m] + cb --
    int wn3 = wave * 64;
    floatx4 acc3[2][4] = {};
    for (int k0 = 0; k0 < M_; k0 += 32) {
        short8 ah[2], al[2], bh3[4];
#pragma unroll
        for (int nt = 0; nt < 4; ++nt)
            bh3[nt] = *(const short8*)&Hm[(long)(wn3 + nt * 16 + lr) * M_ + k0 + lq * 8];
#pragma unroll
        for (int mt = 0; mt < 2; ++mt) {
            ah[mt] = *(const short8*)&Wh[(mt * 16 + lr) * WTPAD + k0 + lq * 8];
            al[mt] = *(const short8*)&Wl[(mt * 16 + lr) * WTPAD + k0 + lq * 8];
        }
#pragma unroll
        for (int mt = 0; mt < 2; ++mt)
#pragma unroll
            for (int nt = 0; nt < 4; ++nt) {
                acc3[mt][nt] = __builtin_amdgcn_mfma_f32_16x16x32_bf16(
                    ah[mt], bh3[nt], acc3[mt][nt], 0, 0, 0);
                acc3[mt][nt] = __builtin_amdgcn_mfma_f32_16x16x32_bf16(
                    al[mt], bh3[nt], acc3[mt][nt], 0, 0, 0);
            }
    }

    float dv[4];
#pragma unroll
    for (int nt = 0; nt < 4; ++nt)
        dv[nt] = DinvN[b * N_ + wn3 + nt * 16 + lr];
    float cb[2][4];
#pragma unroll
    for (int mt = 0; mt < 2; ++mt)
#pragma unroll
        for (int r4 = 0; r4 < 4; ++r4)
            cb[mt][r4] = convb[h0 + mt * 16 + lq * 4 + r4];
#pragma unroll
    for (int mt = 0; mt < 2; ++mt)
#pragma unroll
        for (int nt = 0; nt < 4; ++nt)
#pragma unroll
            for (int r4 = 0; r4 < 4; ++r4)
                acc3[mt][nt][r4] = acc3[mt][nt][r4] * dv[nt] + cb[mt][r4];

    float ps[2][4], pq[2][4];
#pragma unroll
    for (int mt = 0; mt < 2; ++mt)
#pragma unroll
        for (int r4 = 0; r4 < 4; ++r4) {
            float s = 0.f, q = 0.f;
#pragma unroll
            for (int nt = 0; nt < 4; ++nt) {
                float v = acc3[mt][nt][r4];
                s += v; q += v * v;
            }
            ps[mt][r4] = s; pq[mt][r4] = q;
        }
#pragma unroll
    for (int mask = 1; mask <= 8; mask <<= 1) {
#pragma unroll
        for (int mt = 0; mt < 2; ++mt)
#pragma unroll
            for (int r4 = 0; r4 < 4; ++r4) {
                ps[mt][r4] += __shfl_xor(ps[mt][r4], mask);
                pq[mt][r4] += __shfl_xor(pq[mt][r4], mask);
            }
    }
    if (lr == 0) {
#pragma unroll
        for (int mt = 0; mt < 2; ++mt)
#pragma unroll
            for (int r4 = 0; r4 < 4; ++r4) {
                int row = mt * 16 + lq * 4 + r4;
                rsum[row * 8 + wave] = ps[mt][r4];
                rsq[row * 8 + wave]  = pq[mt][r4];
            }
    }
    __syncthreads();
    if (tid < 32) {
        float s = 0.f, s2 = 0.f;
#pragma unroll
        for (int w = 0; w < 8; ++w) { s += rsum[tid * 8 + w]; s2 += rsq[tid * 8 + w]; }
        float mu  = s * (1.0f / N_);
        float var = fmaxf(s2 * (1.0f / N_) - mu * mu, 0.f);
        float sc  = gamma[h0 + tid] * rsqrtf(var + EPS_);
        prm[tid] = make_float2(sc, beta[h0 + tid] - mu * sc);
    }
    __syncthreads();

    unsigned short* ab = actOut + (long)b * H_ * N_;
#pragma unroll
    for (int mt = 0; mt < 2; ++mt)
#pragma unroll
        for (int r4 = 0; r4 < 4; ++r4) {
            int row = mt * 16 + lq * 4 + r4;
            float2 p = prm[row];
#pragma unroll
            for (int nt = 0; nt < 4; ++nt) {
                float y = fmaxf(acc3[mt][nt][r4] * p.x + p.y, 0.f);
                unsigned short hv = f2bf(y);
                long o = (long)(h0 + row) * N_ + wn3 + nt * 16 + lr;
                ab[o] = hv;
                ab[actLo + o] = f2bf(y - bf2f(hv));
            }
        }
}

// ===== decoder: out[n][p] = sum_h (h[h][n]+act[h][n]) * Wdec[h][p] + bdec ==
__global__ __launch_bounds__(256, 2) void decoder_kernel(
    const unsigned short* __restrict__ hAct,   // h hi plane [B][H][N]
    const unsigned short* __restrict__ sAct,   // social hi plane
    const float* __restrict__ Wdec, const float* __restrict__ bdec,
    float* __restrict__ out)
{
    __shared__ float ct[64 * 65];
    __shared__ float wd[256 * 25];
    int n0 = blockIdx.x * 64, b = blockIdx.y;
    int tid = threadIdx.x;
    for (int i = tid; i < 256 * 24; i += 256)
        wd[(i / 24) * 25 + (i % 24)] = Wdec[i];

    const unsigned short* hb = hAct + (long)b * H_ * N_;
    const unsigned short* sb = sAct + (long)b * H_ * N_;
    int x = tid & 63, y0 = tid >> 6;

    int n = tid >> 2;
    int p0 = (tid & 3) * 6;
    float acc[6] = {};

    for (int k0 = 0; k0 < H_; k0 += 64) {
        __syncthreads();
#pragma unroll
        for (int i = 0; i < 16; ++i) {
            int y = y0 * 16 + i;
            long o = (long)(k0 + y) * N_ + n0 + x;
            ct[x * 65 + y] = bf2f(hb[o]) + bf2f(sb[o]);
        }
        __syncthreads();
        const float* crow = &ct[n * 65];
#pragma unroll 8
        for (int kk = 0; kk < 64; ++kk) {
            float a = crow[kk];
            const float* wrow = &wd[(k0 + kk) * 25 + p0];
#pragma unroll
            for (int j = 0; j < 6; ++j)
                acc[j] += a * wrow[j];
        }
    }
    long ob = ((long)b * N_ + n0 + n) * P2_ + p0;
#pragma unroll
    for (int j = 0; j < 6; ++j)
        out[ob + j] = acc[j] + bdec[p0 + j];
}

// --------------------------------------------------------------------------
extern "C" void kernel_launch(void* const* d_in, const int* in_sizes, int n_in,
                              void* d_out, int out_size, void* d_ws, size_t ws_size,
                              hipStream_t stream) {
    const float* obs    = (const float*)d_in[0];
    const int*   hyper  = (const int*)d_in[1];
    const float* Wenc   = (const float*)d_in[2];
    const float* benc   = (const float*)d_in[3];
    const float* thetas = (const float*)d_in[4];
    const float* convb  = (const float*)d_in[5];
    const float* gammas = (const float*)d_in[6];
    const float* betas  = (const float*)d_in[7];
    const float* Wdec   = (const float*)d_in[8];
    const float* bdec   = (const float*)d_in[9];
    float* out = (float*)d_out;

    char* w = (char*)d_ws;
    auto alloc = [&](size_t bytes) { char* p = w; w += (bytes + 255) & ~255ULL; return p; };
    float* DinvN = (float*)alloc((size_t)B_ * N_ * 4);
    float* degP  = (float*)alloc((size_t)B_ * 8 * M_ * 4);
    unsigned short* Hmat  = (unsigned short*)alloc((size_t)B_ * N_ * M_ * 2);
    unsigned short* HmatT = (unsigned short*)alloc((size_t)B_ * M_ * N_ * 2);
    unsigned short* act0  = (unsigned short*)alloc((size_t)B_ * H_ * N_ * 2 * 2);
    unsigned short* act1  = (unsigned short*)alloc((size_t)B_ * H_ * N_ * 2 * 2);
    unsigned short* act2  = (unsigned short*)alloc((size_t)B_ * H_ * N_ * 2 * 2);
    unsigned short* thT   = (unsigned short*)alloc((size_t)L_ * H_ * H_ * 2 * 2);
    unsigned short* Zg    = (unsigned short*)alloc((size_t)B_ * M_ * H_ * 2 * 2);

    const long actLo = (long)B_ * H_ * N_;
    const long thLo  = (long)L_ * H_ * H_;
    const long zLo   = (long)B_ * M_ * H_;

    prep_kernel<<<816, 512, 0, stream>>>(
        obs, Wenc, benc, act0, actLo,
        hyper, Hmat, HmatT, DinvN, degP,
        thetas, thT, thLo);

    // act0 stays pristine as h; layers rotate act0 -> act1 -> act2 -> act1
    unsigned short* bufs[4] = { act0, act1, act2, act1 };
    for (int l = 0; l < L_; ++l) {
        z_kernel<<<dim3(B_, 4), 256, 0, stream>>>(
            HmatT, bufs[l], actLo, degP, Zg, zLo);
        wh_kernel<<<512, 512, 0, stream>>>(
            Zg, zLo, Hmat, thT + (size_t)l * H_ * H_, thLo,
            DinvN, convb + (size_t)l * H_,
            gammas + (size_t)l * H_, betas + (size_t)l * H_, bufs[l + 1], actLo);
    }
    // fused comb + decoder: h = act0 hi, social = final hi
    decoder_kernel<<<dim3(8, B_), 256, 0, stream>>>(
        act0, bufs[L_], Wdec, bdec, out);
}

// Round 18
// 217.504 us; speedup vs baseline: 1.3268x; 1.3268x over previous
//
#include <hip/hip_runtime.h>
#include <hip/hip_bf16.h>

#define B_   64
#define N_   512
#define T_   8
#define DIN_ 2
#define H_   256
#define L_   3
#define E_   8192
#define M_   128
#define P2_  24   // P*2
#define EPS_ 1e-5f

#define WTPAD 136

typedef __attribute__((ext_vector_type(8))) short short8;
typedef __attribute__((ext_vector_type(4))) float floatx4;

__device__ __forceinline__ unsigned short f2bf(float f) {
    union { float f; unsigned u; } v; v.f = f;
    unsigned r = v.u + 0x7FFF + ((v.u >> 16) & 1);
    return (unsigned short)(r >> 16);
}
__device__ __forceinline__ float bf2f(unsigned short h) {
    union { unsigned u; float f; } v; v.u = (unsigned)h << 16; return v.f;
}

// ===== prep: encoder (512 blks, 32 rows) + build (512) + thetaT (48) ======
__global__ __launch_bounds__(512, 4) void prep_kernel(
    const float* __restrict__ obs, const float* __restrict__ Wenc,
    const float* __restrict__ benc,
    unsigned short* __restrict__ actT, long actLo,
    const int* __restrict__ idx, unsigned short* __restrict__ Hmat,
    unsigned short* __restrict__ HmatT, float* __restrict__ DinvN,
    float* __restrict__ degP,
    const float* __restrict__ thetas, unsigned short* __restrict__ thT, long thLo)
{
    __shared__ __align__(16) char u[33024];
    int bid = blockIdx.x, tid = threadIdx.x;
    if (bid < 512) {
        // ---- encoder role: 32 h-rows per block ----
        float* ot = (float*)u;   // [16][513]
        int x8 = bid & 7, s = bid >> 3;
        int b = ((s >> 3) << 3) | x8;      // all 8 chunks of b on XCD b%8
        int h0 = (s & 7) * 32;
        const float4* src = (const float4*)(obs + (long)b * N_ * 16);
        for (int i = tid; i < 2048; i += 512) {
            float4 v = src[i];
            int n = i >> 2, k4 = (i & 3) << 2;
            ot[(k4 + 0) * 513 + n] = v.x;
            ot[(k4 + 1) * 513 + n] = v.y;
            ot[(k4 + 2) * 513 + n] = v.z;
            ot[(k4 + 3) * 513 + n] = v.w;
        }
        __syncthreads();
        int wave = tid >> 6, lane = tid & 63;
        int cbase = h0 + wave * 4;
        float w0[4], w1[4], bb[4];
#pragma unroll
        for (int i = 0; i < 4; ++i) {
            w0[i] = Wenc[cbase + i];
            w1[i] = Wenc[H_ + cbase + i];
            bb[i] = benc[cbase + i];
        }
        for (int j = 0; j < 8; ++j) {
            int n = j * 64 + lane;
            float x0[8], x1[8];
#pragma unroll
            for (int t = 0; t < 8; ++t) {
                x0[t] = ot[(2 * t) * 513 + n];
                x1[t] = ot[(2 * t + 1) * 513 + n];
            }
#pragma unroll
            for (int i = 0; i < 4; ++i) {
                float acc = 0.f;
#pragma unroll
                for (int t = 0; t < 8; ++t)
                    acc += fmaxf(x0[t] * w0[i] + x1[t] * w1[i] + bb[i], 0.f);
                acc *= 0.125f;
                long o = ((long)b * H_ + cbase + i) * N_ + n;
                unsigned short hv = f2bf(acc);
                actT[o] = hv;
                actT[actLo + o] = f2bf(acc - bf2f(hv));
            }
        }
    } else if (bid < 1024) {
        // ---- incidence build role ----
        unsigned* cnt = (unsigned*)u;    // [64][129]
        int id2 = bid - 512;
        int x8 = id2 & 7, s = id2 >> 3;
        int b = ((s >> 3) << 3) | x8;    // all 8 chunks of b on XCD b%8
        int chunk = s & 7;
        int c0 = chunk * 64;
        for (int i = tid; i < 64 * 129; i += 512) cnt[i] = 0;
        __syncthreads();
        const int* nodes = idx + (long)b * 2 * E_;
        const int* edges = nodes + E_;
        for (int e = tid; e < E_; e += 512) {
            int n = nodes[e];
            if ((n >> 6) == chunk) atomicAdd(&cnt[(n & 63) * 129 + edges[e]], 1u);
        }
        __syncthreads();
        for (int i = tid; i < 64 * 128; i += 512) {
            int r = i >> 7, m = i & 127;
            Hmat[((long)(b * N_ + c0 + r)) * M_ + m] = f2bf((float)cnt[r * 129 + m]);
        }
        for (int i = tid; i < 64 * 128; i += 512) {
            int m = i >> 6, r = i & 63;
            HmatT[((long)(b * M_ + m)) * N_ + c0 + r] = f2bf((float)cnt[r * 129 + m]);
        }
        if (tid < 64) {
            unsigned s2 = 0;
#pragma unroll 8
            for (int m = 0; m < 128; ++m) s2 += cnt[tid * 129 + m];
            DinvN[b * N_ + c0 + tid] = 1.0f / fmaxf((float)s2, 1.0f);
        } else if (tid < 192) {
            int m = tid - 64;
            unsigned s2 = 0;
#pragma unroll 8
            for (int r = 0; r < 64; ++r) s2 += cnt[r * 129 + m];
            degP[((long)b * 8 + chunk) * M_ + m] = (float)s2;
        }
    } else {
        // ---- thetaT split-bf16 transpose role ----
        float (*tile)[65] = (float(*)[65])u;
        int sub = bid - 1024;                // 0..47
        int cx = sub & 3, ry = (sub >> 2) & 3, l = sub >> 4;
        int r0 = ry * 64, c0 = cx * 64;
        const float* ib = thetas + (long)l * H_ * H_;
        unsigned short* ob = thT + (long)l * H_ * H_;
        int x = tid & 63, y0 = tid >> 6;
#pragma unroll
        for (int i = 0; i < 8; ++i) {
            int y = y0 * 8 + i;
            tile[y][x] = ib[(long)(r0 + y) * H_ + c0 + x];
        }
        __syncthreads();
#pragma unroll
        for (int i = 0; i < 8; ++i) {
            int y = y0 * 8 + i;
            float v = tile[x][y];
            unsigned short hv = f2bf(v);
            long o = (long)(c0 + y) * H_ + r0 + x;
            ob[o] = hv;
            ob[thLo + o] = f2bf(v - bf2f(hv));
        }
    }
}

// ===== z: Z[m][h'] = Binv[m] * sum_n HT[m][n]*act[h'][n], split out =======
// grid (64, 4): block (b, q) computes cols q*64..+63. id%8 = b%8 (XCD-local).
__global__ __launch_bounds__(256, 4) void z_kernel(
    const unsigned short* __restrict__ HmatT,
    const unsigned short* __restrict__ actIn, long actLo,
    const float* __restrict__ degP,
    unsigned short* __restrict__ Zg, long zLo)
{
    __shared__ __align__(16) unsigned short As1[128 * 40];
    __shared__ __align__(16) unsigned short Bh[64 * 40];
    __shared__ __align__(16) unsigned short Bl[64 * 40];
    __shared__ float binv[128];
    int b = blockIdx.x, hs = blockIdx.y * 64;
    int tid = threadIdx.x, wave = tid >> 6, lane = tid & 63;
    int lr = lane & 15, lq = lane >> 4;
    int wm = (wave & 1) * 64, wn = (wave >> 1) * 32;
    const unsigned short* HT   = HmatT + (long)b * M_ * N_;
    const unsigned short* aInH = actIn + (long)b * H_ * N_ + (long)hs * N_;
    const unsigned short* aInL = actIn + actLo + (long)b * H_ * N_ + (long)hs * N_;

    if (tid < 128) {
        float s = 0.f;
        const float* dp = degP + (long)b * 8 * M_ + tid;
#pragma unroll
        for (int c = 0; c < 8; ++c) s += dp[c * M_];
        binv[tid] = 1.0f / fmaxf(s, 1.0f);
    }

    floatx4 acc[4][2] = {};
    int r0 = tid >> 2, ck = (tid & 3) << 3;
    int r1 = r0 + 64;
    uint4 pA0 = *(const uint4*)&HT[(long)r0 * N_ + ck];
    uint4 pA1 = *(const uint4*)&HT[(long)r1 * N_ + ck];
    uint4 pBh = *(const uint4*)&aInH[(long)r0 * N_ + ck];
    uint4 pBl = *(const uint4*)&aInL[(long)r0 * N_ + ck];
    for (int k0 = 0; k0 < N_; k0 += 32) {
        __syncthreads();
        *(uint4*)&As1[r0 * 40 + ck] = pA0;
        *(uint4*)&As1[r1 * 40 + ck] = pA1;
        *(uint4*)&Bh[r0 * 40 + ck]  = pBh;
        *(uint4*)&Bl[r0 * 40 + ck]  = pBl;
        __syncthreads();
        int kn = k0 + 32;
        if (kn < N_) {
            pA0 = *(const uint4*)&HT[(long)r0 * N_ + kn + ck];
            pA1 = *(const uint4*)&HT[(long)r1 * N_ + kn + ck];
            pBh = *(const uint4*)&aInH[(long)r0 * N_ + kn + ck];
            pBl = *(const uint4*)&aInL[(long)r0 * N_ + kn + ck];
        }
        short8 af[4], bh[2], bl[2];
#pragma unroll
        for (int mt = 0; mt < 4; ++mt)
            af[mt] = *(const short8*)&As1[(wm + mt * 16 + lr) * 40 + lq * 8];
#pragma unroll
        for (int nt = 0; nt < 2; ++nt) {
            bh[nt] = *(const short8*)&Bh[(wn + nt * 16 + lr) * 40 + lq * 8];
            bl[nt] = *(const short8*)&Bl[(wn + nt * 16 + lr) * 40 + lq * 8];
        }
#pragma unroll
        for (int mt = 0; mt < 4; ++mt)
#pragma unroll
            for (int nt = 0; nt < 2; ++nt) {
                acc[mt][nt] = __builtin_amdgcn_mfma_f32_16x16x32_bf16(
                    af[mt], bh[nt], acc[mt][nt], 0, 0, 0);
                acc[mt][nt] = __builtin_amdgcn_mfma_f32_16x16x32_bf16(
                    af[mt], bl[nt], acc[mt][nt], 0, 0, 0);
            }
    }
#pragma unroll
    for (int mt = 0; mt < 4; ++mt)
#pragma unroll
        for (int r4 = 0; r4 < 4; ++r4) {
            int m = wm + mt * 16 + lq * 4 + r4;
            float rsB = binv[m];
#pragma unroll
            for (int nt = 0; nt < 2; ++nt) {
                float v = acc[mt][nt][r4] * rsB;
                unsigned short hv = f2bf(v);
                long o = ((long)b * M_ + m) * H_ + hs + wn + nt * 16 + lr;
                Zg[o] = hv;
                Zg[zLo + o] = f2bf(v - bf2f(hv));
            }
        }
}

// ===== wh: W=Theta^T Z^T ; hc^T=Dinv(W Hm^T)+cb ; BN ; ReLU ; split write ==
__global__ __launch_bounds__(512, 4) void wh_kernel(
    const unsigned short* __restrict__ Zg, long zLo,
    const unsigned short* __restrict__ Hmat,
    const unsigned short* __restrict__ thT, long thLo,   // pre-offset to layer
    const float* __restrict__ DinvN, const float* __restrict__ convb,
    const float* __restrict__ gamma, const float* __restrict__ beta,
    unsigned short* __restrict__ actOut, long actLo)
{
    __shared__ __align__(16) char lds[28160];
    unsigned short* Zch  = (unsigned short*)lds;            // [128][40]
    unsigned short* Zcl  = Zch + 128 * 40;
    unsigned short* As2h = Zcl + 128 * 40;                  // [32][40]
    unsigned short* As2l = As2h + 32 * 40;                  // end 25600 B
    unsigned short* Wh   = (unsigned short*)lds;            // [32][136] overlap
    unsigned short* Wl   = Wh + 32 * WTPAD;                 // end 17408 B
    float* rsum = (float*)(lds + 25600);                    // [32][8]
    float* rsq  = rsum + 256;
    float2* prm = (float2*)(rsq + 256);                     // [32]

    int id = blockIdx.x;
    int xcd = id & 7, slot = id >> 3;
    int chunk = slot & 7;
    int b  = ((slot >> 3) << 3) | xcd;
    int h0 = chunk * 32;

    int tid = threadIdx.x, wave = tid >> 6, lane = tid & 63;
    int lr = lane & 15, lq = lane >> 4;
    const unsigned short* Zb = Zg + (long)b * M_ * H_;
    const unsigned short* Hm = Hmat + (long)b * N_ * M_;

    // ---- stage 2: W[h 32][m 128] = sum_h' thT[h][h'] * Z[m][h'] ----
    int wm2 = (wave >> 2) * 16, wn2 = (wave & 3) * 32;
    int i2 = tid & 255, pl2 = tid >> 8;
    int r2 = i2 >> 2, ck2 = (i2 & 3) << 3;
    bool thAct = (i2 < 128);
    const unsigned short* thBase = thT + (pl2 ? thLo : 0) + (long)(h0 + r2) * H_ + ck2;
    unsigned short* As2dst = (pl2 ? As2l : As2h) + r2 * 40 + ck2;
    int rz = tid >> 2, ckz = (tid & 3) << 3;
    uint4 pTh = {};
    if (thAct) pTh = *(const uint4*)thBase;
    uint4 pZh = *(const uint4*)&Zb[(long)rz * H_ + ckz];
    uint4 pZl = *(const uint4*)&Zb[zLo + (long)rz * H_ + ckz];
    floatx4 acc2[2] = {};
    for (int k0 = 0; k0 < H_; k0 += 32) {
        __syncthreads();
        if (thAct) *(uint4*)As2dst = pTh;
        *(uint4*)&Zch[rz * 40 + ckz] = pZh;
        *(uint4*)&Zcl[rz * 40 + ckz] = pZl;
        __syncthreads();
        int kn = k0 + 32;
        if (kn < H_) {
            if (thAct) pTh = *(const uint4*)(thBase + kn);
            pZh = *(const uint4*)&Zb[(long)rz * H_ + kn + ckz];
            pZl = *(const uint4*)&Zb[zLo + (long)rz * H_ + kn + ckz];
        }
        short8 ah, al, zb[2], zl[2];
        ah = *(const short8*)&As2h[(wm2 + lr) * 40 + lq * 8];
        al = *(const short8*)&As2l[(wm2 + lr) * 40 + lq * 8];
#pragma unroll
        for (int nt = 0; nt < 2; ++nt) {
            zb[nt] = *(const short8*)&Zch[(wn2 + nt * 16 + lr) * 40 + lq * 8];
            zl[nt] = *(const short8*)&Zcl[(wn2 + nt * 16 + lr) * 40 + lq * 8];
        }
#pragma unroll
        for (int nt = 0; nt < 2; ++nt) {
            acc2[nt] = __builtin_amdgcn_mfma_f32_16x16x32_bf16(ah, zb[nt], acc2[nt], 0, 0, 0);
            acc2[nt] = __builtin_amdgcn_mfma_f32_16x16x32_bf16(ah, zl[nt], acc2[nt], 0, 0, 0);
            acc2[nt] = __builtin_amdgcn_mfma_f32_16x16x32_bf16(al, zb[nt], acc2[nt], 0, 0, 0);
        }
    }
    __syncthreads();
#pragma unroll
    for (int r4 = 0; r4 < 4; ++r4) {
        int row = wm2 + lq * 4 + r4;
#pragma unroll
        for (int nt = 0; nt < 2; ++nt) {
            int col = wn2 + nt * 16 + lr;
            float v = acc2[nt][r4];
            unsigned short hv = f2bf(v);
            Wh[row * WTPAD + col] = hv;
            Wl[row * WTPAD + col] = f2bf(v - bf2f(hv));
        }
    }
    __syncthreads();

    // ---- stage 3: hc^T[h 32][n 512] = Dinv[n]*sum_m W[h][m]*Hm[n][m] + cb --
    int wn3 = wave * 64;
    floatx4 acc3[2][4] = {};
    for (int k0 = 0; k0 < M_; k0 += 32) {
        short8 ah[2], al[2], bh3[4];
#pragma unroll
        for (int nt = 0; nt < 4; ++nt)
            bh3[nt] = *(const short8*)&Hm[(long)(wn3 + nt * 16 + lr) * M_ + k0 + lq * 8];
#pragma unroll
        for (int mt = 0; mt < 2; ++mt) {
            ah[mt] = *(const short8*)&Wh[(mt * 16 + lr) * WTPAD + k0 + lq * 8];
            al[mt] = *(const short8*)&Wl[(mt * 16 + lr) * WTPAD + k0 + lq * 8];
        }
#pragma unroll
        for (int mt = 0; mt < 2; ++mt)
#pragma unroll
            for (int nt = 0; nt < 4; ++nt) {
                acc3[mt][nt] = __builtin_amdgcn_mfma_f32_16x16x32_bf16(
                    ah[mt], bh3[nt], acc3[mt][nt], 0, 0, 0);
                acc3[mt][nt] = __builtin_amdgcn_mfma_f32_16x16x32_bf16(
                    al[mt], bh3[nt], acc3[mt][nt], 0, 0, 0);
            }
    }

    float dv[4];
#pragma unroll
    for (int nt = 0; nt < 4; ++nt)
        dv[nt] = DinvN[b * N_ + wn3 + nt * 16 + lr];
    float cb[2][4];
#pragma unroll
    for (int mt = 0; mt < 2; ++mt)
#pragma unroll
        for (int r4 = 0; r4 < 4; ++r4)
            cb[mt][r4] = convb[h0 + mt * 16 + lq * 4 + r4];
#pragma unroll
    for (int mt = 0; mt < 2; ++mt)
#pragma unroll
        for (int nt = 0; nt < 4; ++nt)
#pragma unroll
            for (int r4 = 0; r4 < 4; ++r4)
                acc3[mt][nt][r4] = acc3[mt][nt][r4] * dv[nt] + cb[mt][r4];

    float ps[2][4], pq[2][4];
#pragma unroll
    for (int mt = 0; mt < 2; ++mt)
#pragma unroll
        for (int r4 = 0; r4 < 4; ++r4) {
            float s = 0.f, q = 0.f;
#pragma unroll
            for (int nt = 0; nt < 4; ++nt) {
                float v = acc3[mt][nt][r4];
                s += v; q += v * v;
            }
            ps[mt][r4] = s; pq[mt][r4] = q;
        }
#pragma unroll
    for (int mask = 1; mask <= 8; mask <<= 1) {
#pragma unroll
        for (int mt = 0; mt < 2; ++mt)
#pragma unroll
            for (int r4 = 0; r4 < 4; ++r4) {
                ps[mt][r4] += __shfl_xor(ps[mt][r4], mask);
                pq[mt][r4] += __shfl_xor(pq[mt][r4], mask);
            }
    }
    if (lr == 0) {
#pragma unroll
        for (int mt = 0; mt < 2; ++mt)
#pragma unroll
            for (int r4 = 0; r4 < 4; ++r4) {
                int row = mt * 16 + lq * 4 + r4;
                rsum[row * 8 + wave] = ps[mt][r4];
                rsq[row * 8 + wave]  = pq[mt][r4];
            }
    }
    __syncthreads();
    if (tid < 32) {
        float s = 0.f, s2 = 0.f;
#pragma unroll
        for (int w = 0; w < 8; ++w) { s += rsum[tid * 8 + w]; s2 += rsq[tid * 8 + w]; }
        float mu  = s * (1.0f / N_);
        float var = fmaxf(s2 * (1.0f / N_) - mu * mu, 0.f);
        float sc  = gamma[h0 + tid] * rsqrtf(var + EPS_);
        prm[tid] = make_float2(sc, beta[h0 + tid] - mu * sc);
    }
    __syncthreads();

    unsigned short* ab = actOut + (long)b * H_ * N_;
#pragma unroll
    for (int mt = 0; mt < 2; ++mt)
#pragma unroll
        for (int r4 = 0; r4 < 4; ++r4) {
            int row = mt * 16 + lq * 4 + r4;
            float2 p = prm[row];
#pragma unroll
            for (int nt = 0; nt < 4; ++nt) {
                float y = fmaxf(acc3[mt][nt][r4] * p.x + p.y, 0.f);
                unsigned short hv = f2bf(y);
                long o = (long)(h0 + row) * N_ + wn3 + nt * 16 + lr;
                ab[o] = hv;
                ab[actLo + o] = f2bf(y - bf2f(hv));
            }
        }
}

// ===== decoder: out[n][p] = sum_h (h[h][n]+act[h][n]) * Wdec[h][p] + bdec ==
__global__ __launch_bounds__(256, 2) void decoder_kernel(
    const unsigned short* __restrict__ hAct,   // h hi plane [B][H][N]
    const unsigned short* __restrict__ sAct,   // social hi plane
    const float* __restrict__ Wdec, const float* __restrict__ bdec,
    float* __restrict__ out)
{
    __shared__ float ct[64 * 65];
    __shared__ float wd[256 * 25];
    int n0 = blockIdx.x * 64, b = blockIdx.y;
    int tid = threadIdx.x;
    for (int i = tid; i < 256 * 24; i += 256)
        wd[(i / 24) * 25 + (i % 24)] = Wdec[i];

    const unsigned short* hb = hAct + (long)b * H_ * N_;
    const unsigned short* sb = sAct + (long)b * H_ * N_;
    int x = tid & 63, y0 = tid >> 6;

    int n = tid >> 2;
    int p0 = (tid & 3) * 6;
    float acc[6] = {};

    for (int k0 = 0; k0 < H_; k0 += 64) {
        __syncthreads();
#pragma unroll
        for (int i = 0; i < 16; ++i) {
            int y = y0 * 16 + i;
            long o = (long)(k0 + y) * N_ + n0 + x;
            ct[x * 65 + y] = bf2f(hb[o]) + bf2f(sb[o]);
        }
        __syncthreads();
        const float* crow = &ct[n * 65];
#pragma unroll 8
        for (int kk = 0; kk < 64; ++kk) {
            float a = crow[kk];
            const float* wrow = &wd[(k0 + kk) * 25 + p0];
#pragma unroll
            for (int j = 0; j < 6; ++j)
                acc[j] += a * wrow[j];
        }
    }
    long ob = ((long)b * N_ + n0 + n) * P2_ + p0;
#pragma unroll
    for (int j = 0; j < 6; ++j)
        out[ob + j] = acc[j] + bdec[p0 + j];
}

// --------------------------------------------------------------------------
extern "C" void kernel_launch(void* const* d_in, const int* in_sizes, int n_in,
                              void* d_out, int out_size, void* d_ws, size_t ws_size,
                              hipStream_t stream) {
    const float* obs    = (const float*)d_in[0];
    const int*   hyper  = (const int*)d_in[1];
    const float* Wenc   = (const float*)d_in[2];
    const float* benc   = (const float*)d_in[3];
    const float* thetas = (const float*)d_in[4];
    const float* convb  = (const float*)d_in[5];
    const float* gammas = (const float*)d_in[6];
    const float* betas  = (const float*)d_in[7];
    const float* Wdec   = (const float*)d_in[8];
    const float* bdec   = (const float*)d_in[9];
    float* out = (float*)d_out;

    char* w = (char*)d_ws;
    auto alloc = [&](size_t bytes) { char* p = w; w += (bytes + 255) & ~255ULL; return p; };
    float* DinvN = (float*)alloc((size_t)B_ * N_ * 4);
    float* degP  = (float*)alloc((size_t)B_ * 8 * M_ * 4);
    unsigned short* Hmat  = (unsigned short*)alloc((size_t)B_ * N_ * M_ * 2);
    unsigned short* HmatT = (unsigned short*)alloc((size_t)B_ * M_ * N_ * 2);
    unsigned short* act0  = (unsigned short*)alloc((size_t)B_ * H_ * N_ * 2 * 2);
    unsigned short* act1  = (unsigned short*)alloc((size_t)B_ * H_ * N_ * 2 * 2);
    unsigned short* act2  = (unsigned short*)alloc((size_t)B_ * H_ * N_ * 2 * 2);
    unsigned short* thT   = (unsigned short*)alloc((size_t)L_ * H_ * H_ * 2 * 2);
    unsigned short* Zg    = (unsigned short*)alloc((size_t)B_ * M_ * H_ * 2 * 2);

    const long actLo = (long)B_ * H_ * N_;
    const long thLo  = (long)L_ * H_ * H_;
    const long zLo   = (long)B_ * M_ * H_;

    prep_kernel<<<1072, 512, 0, stream>>>(
        obs, Wenc, benc, act0, actLo,
        hyper, Hmat, HmatT, DinvN, degP,
        thetas, thT, thLo);

    // act0 stays pristine as h; layers rotate act0 -> act1 -> act2 -> act1
    unsigned short* bufs[4] = { act0, act1, act2, act1 };
    for (int l = 0; l < L_; ++l) {
        z_kernel<<<dim3(B_, 4), 256, 0, stream>>>(
            HmatT, bufs[l], actLo, degP, Zg, zLo);
        wh_kernel<<<512, 512, 0, stream>>>(
            Zg, zLo, Hmat, thT + (size_t)l * H_ * H_, thLo,
            DinvN, convb + (size_t)l * H_,
            gammas + (size_t)l * H_, betas + (size_t)l * H_, bufs[l + 1], actLo);
    }
    // fused comb + decoder: h = act0 hi, social = final hi
    decoder_kernel<<<dim3(8, B_), 256, 0, stream>>>(
        act0, bufs[L_], Wdec, bdec, out);
}